// Round 3
// baseline (428.792 us; speedup 1.0000x reference)
//
#include <hip/hip_runtime.h>
#include <hip/hip_bf16.h>
#include <stdint.h>

typedef __bf16 bf16_t;
typedef __bf16 bf16x8 __attribute__((ext_vector_type(8)));
typedef __bf16 bf16x4 __attribute__((ext_vector_type(4)));
typedef float f32x4 __attribute__((ext_vector_type(4)));

#define AS1 __attribute__((address_space(1)))
#define AS3 __attribute__((address_space(3)))

static __device__ __forceinline__ void gload_lds16(const void* g, void* l) {
  __builtin_amdgcn_global_load_lds((const AS1 void*)g, (AS3 void*)l, 16, 0, 0);
}

// ---------------- fp32 -> bf16 convert (vectorized x4) ----------------
__global__ void cvt_f32_bf16(const float* __restrict__ in, bf16_t* __restrict__ out, int n4) {
  int i = blockIdx.x * blockDim.x + threadIdx.x;
  if (i >= n4) return;
  float4 v = ((const float4*)in)[i];
  bf16x4 o;
  o[0] = (bf16_t)v.x; o[1] = (bf16_t)v.y; o[2] = (bf16_t)v.z; o[3] = (bf16_t)v.w;
  *(bf16x4*)(out + (size_t)i * 4) = o;
}

// ---------------- GEMM C = A(MxK) * B(NxK)^T, bf16 in, fp32 acc ----------------
template<int MODE>
__global__ __launch_bounds__(256) void gemm_bt(
    const bf16_t* __restrict__ A, const bf16_t* __restrict__ Bw,
    const float* __restrict__ bias, void* __restrict__ Cout,
    int M, int N, int K)
{
  __shared__ bf16_t As[128 * 32];
  __shared__ bf16_t Bs[128 * 32];
  const int tid = threadIdx.x;
  const int wave = tid >> 6, lane = tid & 63;
  const int l15 = lane & 15, l4 = lane >> 4;
  const int m0 = blockIdx.y * 128, n0 = blockIdx.x * 128;
  const int wm = (wave >> 1) * 64, wn = (wave & 1) * 64;
  f32x4 acc[4][4] = {};

  const int r = tid >> 2;
  const int cb = (tid & 3) * 16;
  const char* gA0 = (const char*)(A + (size_t)(m0 + r) * K) + cb;
  const char* gA1 = (const char*)(A + (size_t)(m0 + 64 + r) * K) + cb;
  const char* gB0 = (const char*)(Bw + (size_t)(n0 + r) * K) + cb;
  const char* gB1 = (const char*)(Bw + (size_t)(n0 + 64 + r) * K) + cb;
  char* lA = (char*)As + tid * 16;
  char* lB = (char*)Bs + tid * 16;

  for (int k0 = 0; k0 < K; k0 += 32) {
    const size_t koff = (size_t)k0 * 2;
    gload_lds16(gA0 + koff, lA);
    gload_lds16(gA1 + koff, lA + 4096);
    gload_lds16(gB0 + koff, lB);
    gload_lds16(gB1 + koff, lB + 4096);
    __syncthreads();
    bf16x8 af[4], bfr[4];
#pragma unroll
    for (int mt = 0; mt < 4; ++mt)
      af[mt] = *(const bf16x8*)&As[(wm + mt * 16 + l15) * 32 + l4 * 8];
#pragma unroll
    for (int nt = 0; nt < 4; ++nt)
      bfr[nt] = *(const bf16x8*)&Bs[(wn + nt * 16 + l15) * 32 + l4 * 8];
#pragma unroll
    for (int mt = 0; mt < 4; ++mt)
#pragma unroll
      for (int nt = 0; nt < 4; ++nt)
        acc[mt][nt] = __builtin_amdgcn_mfma_f32_16x16x32_bf16(af[mt], bfr[nt], acc[mt][nt], 0, 0, 0);
    __syncthreads();
  }

  if (MODE == 0) {
    bf16_t* qkv = (bf16_t*)Cout;
#pragma unroll
    for (int mt = 0; mt < 4; ++mt) {
#pragma unroll
      for (int nt = 0; nt < 4; ++nt) {
        const int col = n0 + wn + nt * 16 + l15;
        const float bv = bias[col];
        const int which = col >> 10;
        const int c = col & 1023;
        const int head = c >> 6, d = c & 63;
#pragma unroll
        for (int i = 0; i < 4; ++i) {
          const int row = m0 + wm + mt * 16 + l4 * 4 + i;
          const int bb = row >> 11, t = row & 2047;
          float v = acc[mt][nt][i] + bv;
          if (which == 0) v *= 0.125f;
          qkv[(size_t)which * 8388608 + ((size_t)((bb * 16 + head) * 2048 + t) << 6) + d] = (bf16_t)v;
        }
      }
    }
  } else {
    float* C = (float*)Cout;
#pragma unroll
    for (int mt = 0; mt < 4; ++mt) {
#pragma unroll
      for (int nt = 0; nt < 4; ++nt) {
        const int col = n0 + wn + nt * 16 + l15;
        const float bv = bias[col];
#pragma unroll
        for (int i = 0; i < 4; ++i) {
          const int row = m0 + wm + mt * 16 + l4 * 4 + i;
          C[(size_t)row * N + col] = acc[mt][nt][i] + bv;
        }
      }
    }
  }
}

// ---------------- one flash tile-step, guaranteed-inline, register state ----
// State is named f32x4 references (NO arrays -> nothing can fall to scratch).
static __device__ __forceinline__ void attn_step(
    const bf16_t* Kt, const bf16_t* VT, bf16_t* Ps,
    const int wave, const int l15, const int l4,
    const bf16x8 aq0, const bf16x8 aq1,
    f32x4& m_i, f32x4& l_i,
    f32x4& o0, f32x4& o1, f32x4& o2, f32x4& o3,
    const bool diag)
{
  f32x4 s0 = {}, s1 = {}, s2 = {}, s3 = {};
  {
    bf16x8 b0 = *(const bf16x8*)&Kt[(0 * 16 + l15) * 72 + l4 * 8];
    bf16x8 b1 = *(const bf16x8*)&Kt[(0 * 16 + l15) * 72 + 32 + l4 * 8];
    s0 = __builtin_amdgcn_mfma_f32_16x16x32_bf16(aq0, b0, s0, 0, 0, 0);
    s0 = __builtin_amdgcn_mfma_f32_16x16x32_bf16(aq1, b1, s0, 0, 0, 0);
  }
  {
    bf16x8 b0 = *(const bf16x8*)&Kt[(1 * 16 + l15) * 72 + l4 * 8];
    bf16x8 b1 = *(const bf16x8*)&Kt[(1 * 16 + l15) * 72 + 32 + l4 * 8];
    s1 = __builtin_amdgcn_mfma_f32_16x16x32_bf16(aq0, b0, s1, 0, 0, 0);
    s1 = __builtin_amdgcn_mfma_f32_16x16x32_bf16(aq1, b1, s1, 0, 0, 0);
  }
  {
    bf16x8 b0 = *(const bf16x8*)&Kt[(2 * 16 + l15) * 72 + l4 * 8];
    bf16x8 b1 = *(const bf16x8*)&Kt[(2 * 16 + l15) * 72 + 32 + l4 * 8];
    s2 = __builtin_amdgcn_mfma_f32_16x16x32_bf16(aq0, b0, s2, 0, 0, 0);
    s2 = __builtin_amdgcn_mfma_f32_16x16x32_bf16(aq1, b1, s2, 0, 0, 0);
  }
  {
    bf16x8 b0 = *(const bf16x8*)&Kt[(3 * 16 + l15) * 72 + l4 * 8];
    bf16x8 b1 = *(const bf16x8*)&Kt[(3 * 16 + l15) * 72 + 32 + l4 * 8];
    s3 = __builtin_amdgcn_mfma_f32_16x16x32_bf16(aq0, b0, s3, 0, 0, 0);
    s3 = __builtin_amdgcn_mfma_f32_16x16x32_bf16(aq1, b1, s3, 0, 0, 0);
  }
  if (diag) {
#pragma unroll
    for (int i = 0; i < 4; ++i) {
      const int q = wave * 16 + l4 * 4 + i;
      if (0 * 16 + l15 > q) s0[i] = -1e30f;
      if (1 * 16 + l15 > q) s1[i] = -1e30f;
      if (2 * 16 + l15 > q) s2[i] = -1e30f;
      if (3 * 16 + l15 > q) s3[i] = -1e30f;
    }
  }
  f32x4 pm;
#pragma unroll
  for (int i = 0; i < 4; ++i)
    pm[i] = fmaxf(fmaxf(s0[i], s1[i]), fmaxf(s2[i], s3[i]));
#pragma unroll
  for (int i = 0; i < 4; ++i) {
    pm[i] = fmaxf(pm[i], __shfl_xor(pm[i], 1));
    pm[i] = fmaxf(pm[i], __shfl_xor(pm[i], 2));
    pm[i] = fmaxf(pm[i], __shfl_xor(pm[i], 4));
    pm[i] = fmaxf(pm[i], __shfl_xor(pm[i], 8));
  }
  f32x4 sc;
#pragma unroll
  for (int i = 0; i < 4; ++i) {
    const float mn = fmaxf(m_i[i], pm[i]);
    sc[i] = __expf(m_i[i] - mn);
    m_i[i] = mn;
  }
  f32x4 rsum;
#pragma unroll
  for (int i = 0; i < 4; ++i) {
    s0[i] = __expf(s0[i] - m_i[i]);
    s1[i] = __expf(s1[i] - m_i[i]);
    s2[i] = __expf(s2[i] - m_i[i]);
    s3[i] = __expf(s3[i] - m_i[i]);
    rsum[i] = (s0[i] + s1[i]) + (s2[i] + s3[i]);
  }
#pragma unroll
  for (int i = 0; i < 4; ++i) {
    rsum[i] += __shfl_xor(rsum[i], 1);
    rsum[i] += __shfl_xor(rsum[i], 2);
    rsum[i] += __shfl_xor(rsum[i], 4);
    rsum[i] += __shfl_xor(rsum[i], 8);
    l_i[i] = l_i[i] * sc[i] + rsum[i];
  }
#pragma unroll
  for (int i = 0; i < 4; ++i) {
    o0[i] *= sc[i]; o1[i] *= sc[i]; o2[i] *= sc[i]; o3[i] *= sc[i];
  }
  // P -> LDS, XOR-swizzled so the 4 l4 row-groups hit disjoint banks
#pragma unroll
  for (int i = 0; i < 4; ++i) {
    const int row = wave * 16 + l4 * 4 + i;
    const int swz = l4 << 4;  // ((row>>2)&3)<<4 == l4<<4
    Ps[row * 72 + ((0 * 16 + l15) ^ swz)] = (bf16_t)s0[i];
    Ps[row * 72 + ((1 * 16 + l15) ^ swz)] = (bf16_t)s1[i];
    Ps[row * 72 + ((2 * 16 + l15) ^ swz)] = (bf16_t)s2[i];
    Ps[row * 72 + ((3 * 16 + l15) ^ swz)] = (bf16_t)s3[i];
  }
  const int prow = wave * 16 + l15;
  const int psw = ((prow >> 2) & 3) << 4;
  bf16x8 pa0 = *(const bf16x8*)&Ps[prow * 72 + ((l4 * 8) ^ psw)];
  bf16x8 pa1 = *(const bf16x8*)&Ps[prow * 72 + ((32 + l4 * 8) ^ psw)];
  {
    bf16x8 vb0 = *(const bf16x8*)&VT[(0 * 16 + l15) * 72 + l4 * 8];
    bf16x8 vb1 = *(const bf16x8*)&VT[(0 * 16 + l15) * 72 + 32 + l4 * 8];
    o0 = __builtin_amdgcn_mfma_f32_16x16x32_bf16(pa0, vb0, o0, 0, 0, 0);
    o0 = __builtin_amdgcn_mfma_f32_16x16x32_bf16(pa1, vb1, o0, 0, 0, 0);
  }
  {
    bf16x8 vb0 = *(const bf16x8*)&VT[(1 * 16 + l15) * 72 + l4 * 8];
    bf16x8 vb1 = *(const bf16x8*)&VT[(1 * 16 + l15) * 72 + 32 + l4 * 8];
    o1 = __builtin_amdgcn_mfma_f32_16x16x32_bf16(pa0, vb0, o1, 0, 0, 0);
    o1 = __builtin_amdgcn_mfma_f32_16x16x32_bf16(pa1, vb1, o1, 0, 0, 0);
  }
  {
    bf16x8 vb0 = *(const bf16x8*)&VT[(2 * 16 + l15) * 72 + l4 * 8];
    bf16x8 vb1 = *(const bf16x8*)&VT[(2 * 16 + l15) * 72 + 32 + l4 * 8];
    o2 = __builtin_amdgcn_mfma_f32_16x16x32_bf16(pa0, vb0, o2, 0, 0, 0);
    o2 = __builtin_amdgcn_mfma_f32_16x16x32_bf16(pa1, vb1, o2, 0, 0, 0);
  }
  {
    bf16x8 vb0 = *(const bf16x8*)&VT[(3 * 16 + l15) * 72 + l4 * 8];
    bf16x8 vb1 = *(const bf16x8*)&VT[(3 * 16 + l15) * 72 + 32 + l4 * 8];
    o3 = __builtin_amdgcn_mfma_f32_16x16x32_bf16(pa0, vb0, o3, 0, 0, 0);
    o3 = __builtin_amdgcn_mfma_f32_16x16x32_bf16(pa1, vb1, o3, 0, 0, 0);
  }
}

// ---------------- causal flash attention, paired q-tiles ----------------
// grid: (16, B*nh), block 256. Block bx handles q-tiles jA=bx, jB=31-bx
// sharing K/V staging -> constant 33 compute-steps per block.
__global__ __launch_bounds__(256, 4) void flash_attn(
    const bf16_t* __restrict__ Qg, const bf16_t* __restrict__ Kg,
    const bf16_t* __restrict__ Vg, bf16_t* __restrict__ Y)
{
  const int T = 2048, HS = 64;
  const int bx = blockIdx.x, bh = blockIdx.y;
  const int jA = bx, jB = 31 - bx;
  const size_t base = (size_t)bh * T * HS;

  __shared__ bf16_t Kt[64 * 72];
  __shared__ bf16_t VT[64 * 72];
  __shared__ bf16_t Ps[64 * 72];

  const int tid = threadIdx.x;
  const int wave = tid >> 6, lane = tid & 63;
  const int l15 = lane & 15, l4 = lane >> 4;

  bf16x8 aqA0, aqA1, aqB0, aqB1;
  {
    const bf16_t* qr = Qg + base + (size_t)(jA * 64 + wave * 16 + l15) * HS;
    aqA0 = *(const bf16x8*)(qr + l4 * 8);
    aqA1 = *(const bf16x8*)(qr + 32 + l4 * 8);
    qr = Qg + base + (size_t)(jB * 64 + wave * 16 + l15) * HS;
    aqB0 = *(const bf16x8*)(qr + l4 * 8);
    aqB1 = *(const bf16x8*)(qr + 32 + l4 * 8);
  }

  f32x4 mA, lA_, mB, lB_;
  f32x4 oA0 = {}, oA1 = {}, oA2 = {}, oA3 = {};
  f32x4 oB0 = {}, oB1 = {}, oB2 = {}, oB3 = {};
#pragma unroll
  for (int i = 0; i < 4; ++i) { mA[i] = mB[i] = -1e30f; lA_[i] = lB_[i] = 0.f; }

  for (int kt = 0; kt <= jB; ++kt) {
    const int k0 = kt * 64;
    __syncthreads();  // prior step's LDS reads complete before restage
    {
      const int kr = tid >> 2;
      const int c16 = (tid & 3) * 16;
      const bf16_t* src = Kg + base + (size_t)(k0 + kr) * HS + c16;
      *(bf16x8*)&Kt[kr * 72 + c16] = *(const bf16x8*)src;
      *(bf16x8*)&Kt[kr * 72 + c16 + 8] = *(const bf16x8*)(src + 8);
      const int vk = lane;
      const int d0 = wave * 16;
      const bf16_t* vrow = Vg + base + (size_t)(k0 + vk) * HS + d0;
      bf16x8 v0 = *(const bf16x8*)vrow;
      bf16x8 v1 = *(const bf16x8*)(vrow + 8);
#pragma unroll
      for (int j = 0; j < 8; ++j) {
        VT[(d0 + j) * 72 + vk] = v0[j];
        VT[(d0 + 8 + j) * 72 + vk] = v1[j];
      }
    }
    __syncthreads();
    attn_step(Kt, VT, Ps, wave, l15, l4, aqB0, aqB1, mB, lB_, oB0, oB1, oB2, oB3, kt == jB);
    if (kt <= jA)
      attn_step(Kt, VT, Ps, wave, l15, l4, aqA0, aqA1, mA, lA_, oA0, oA1, oA2, oA3, kt == jA);
  }

  const int b = bh >> 4, h = bh & 15;
#pragma unroll
  for (int i = 0; i < 4; ++i) {
    const int qa = jA * 64 + wave * 16 + l4 * 4 + i;
    const int qb = jB * 64 + wave * 16 + l4 * 4 + i;
    bf16_t* ya = Y + ((size_t)(b * T + qa)) * 1024 + h * 64 + l15;
    bf16_t* yb2 = Y + ((size_t)(b * T + qb)) * 1024 + h * 64 + l15;
    const float ila = 1.f / lA_[i], ilb = 1.f / lB_[i];
    ya[0]  = (bf16_t)(oA0[i] * ila);
    ya[16] = (bf16_t)(oA1[i] * ila);
    ya[32] = (bf16_t)(oA2[i] * ila);
    ya[48] = (bf16_t)(oA3[i] * ila);
    yb2[0]  = (bf16_t)(oB0[i] * ilb);
    yb2[16] = (bf16_t)(oB1[i] * ilb);
    yb2[32] = (bf16_t)(oB2[i] * ilb);
    yb2[48] = (bf16_t)(oB3[i] * ilb);
  }
}

// ---------------- launch ----------------
extern "C" void kernel_launch(void* const* d_in, const int* in_sizes, int n_in,
                              void* d_out, int out_size, void* d_ws, size_t ws_size,
                              hipStream_t stream) {
  const float* x      = (const float*)d_in[0];
  const float* w_attn = (const float*)d_in[1];
  const float* b_attn = (const float*)d_in[2];
  const float* w_proj = (const float*)d_in[3];
  const float* b_proj = (const float*)d_in[4];
  float* out = (float*)d_out;

  char* ws = (char*)d_ws;
  bf16_t* xb   = (bf16_t*)(ws);
  bf16_t* wab  = (bf16_t*)(ws + 16777216);
  bf16_t* wpb  = (bf16_t*)(ws + 23068672);
  bf16_t* qkvb = (bf16_t*)(ws + 25165824);
  bf16_t* yb   = (bf16_t*)(ws + 75497472);

  cvt_f32_bf16<<<8192, 256, 0, stream>>>(x, xb, 2097152);
  cvt_f32_bf16<<<3072, 256, 0, stream>>>(w_attn, wab, 786432);
  cvt_f32_bf16<<<1024, 256, 0, stream>>>(w_proj, wpb, 262144);

  dim3 g1(24, 64);
  gemm_bt<0><<<g1, 256, 0, stream>>>(xb, wab, b_attn, (void*)qkvb, 8192, 3072, 1024);

  dim3 g2(16, 64);
  flash_attn<<<g2, 256, 0, stream>>>(qkvb, qkvb + 8388608, qkvb + 16777216, yb);

  dim3 g3(8, 64);
  gemm_bt<1><<<g3, 256, 0, stream>>>(yb, wpb, b_proj, (void*)out, 8192, 1024, 1024);
}

// Round 4
// 368.636 us; speedup vs baseline: 1.1632x; 1.1632x over previous
//
#include <hip/hip_runtime.h>
#include <hip/hip_bf16.h>
#include <stdint.h>

typedef __bf16 bf16_t;
typedef __bf16 bf16x8 __attribute__((ext_vector_type(8)));
typedef __bf16 bf16x4 __attribute__((ext_vector_type(4)));
typedef float f32x4 __attribute__((ext_vector_type(4)));

#define AS1 __attribute__((address_space(1)))
#define AS3 __attribute__((address_space(3)))

static __device__ __forceinline__ void gload_lds16(const void* g, void* l) {
  __builtin_amdgcn_global_load_lds((const AS1 void*)g, (AS3 void*)l, 16, 0, 0);
}

// ---------------- fp32 -> bf16 convert (vectorized x4) ----------------
__global__ void cvt_f32_bf16(const float* __restrict__ in, bf16_t* __restrict__ out, int n4) {
  int i = blockIdx.x * blockDim.x + threadIdx.x;
  if (i >= n4) return;
  float4 v = ((const float4*)in)[i];
  bf16x4 o;
  o[0] = (bf16_t)v.x; o[1] = (bf16_t)v.y; o[2] = (bf16_t)v.z; o[3] = (bf16_t)v.w;
  *(bf16x4*)(out + (size_t)i * 4) = o;
}

// ---------------- GEMM C = A(MxK) * B(NxK)^T, bf16 in, fp32 acc ----------------
template<int MODE>
__global__ __launch_bounds__(256) void gemm_bt(
    const bf16_t* __restrict__ A, const bf16_t* __restrict__ Bw,
    const float* __restrict__ bias, void* __restrict__ Cout,
    int M, int N, int K)
{
  __shared__ bf16_t As[128 * 32];
  __shared__ bf16_t Bs[128 * 32];
  const int tid = threadIdx.x;
  const int wave = tid >> 6, lane = tid & 63;
  const int l15 = lane & 15, l4 = lane >> 4;
  const int m0 = blockIdx.y * 128, n0 = blockIdx.x * 128;
  const int wm = (wave >> 1) * 64, wn = (wave & 1) * 64;
  f32x4 acc[4][4] = {};

  const int r = tid >> 2;
  const int cb = (tid & 3) * 16;
  const char* gA0 = (const char*)(A + (size_t)(m0 + r) * K) + cb;
  const char* gA1 = (const char*)(A + (size_t)(m0 + 64 + r) * K) + cb;
  const char* gB0 = (const char*)(Bw + (size_t)(n0 + r) * K) + cb;
  const char* gB1 = (const char*)(Bw + (size_t)(n0 + 64 + r) * K) + cb;
  char* lA = (char*)As + tid * 16;
  char* lB = (char*)Bs + tid * 16;

  for (int k0 = 0; k0 < K; k0 += 32) {
    const size_t koff = (size_t)k0 * 2;
    gload_lds16(gA0 + koff, lA);
    gload_lds16(gA1 + koff, lA + 4096);
    gload_lds16(gB0 + koff, lB);
    gload_lds16(gB1 + koff, lB + 4096);
    __syncthreads();
    bf16x8 af[4], bfr[4];
#pragma unroll
    for (int mt = 0; mt < 4; ++mt)
      af[mt] = *(const bf16x8*)&As[(wm + mt * 16 + l15) * 32 + l4 * 8];
#pragma unroll
    for (int nt = 0; nt < 4; ++nt)
      bfr[nt] = *(const bf16x8*)&Bs[(wn + nt * 16 + l15) * 32 + l4 * 8];
#pragma unroll
    for (int mt = 0; mt < 4; ++mt)
#pragma unroll
      for (int nt = 0; nt < 4; ++nt)
        acc[mt][nt] = __builtin_amdgcn_mfma_f32_16x16x32_bf16(af[mt], bfr[nt], acc[mt][nt], 0, 0, 0);
    __syncthreads();
  }

  if (MODE == 0) {
    bf16_t* qkv = (bf16_t*)Cout;
#pragma unroll
    for (int mt = 0; mt < 4; ++mt) {
#pragma unroll
      for (int nt = 0; nt < 4; ++nt) {
        const int col = n0 + wn + nt * 16 + l15;
        const float bv = bias[col];
        const int which = col >> 10;
        const int c = col & 1023;
        const int head = c >> 6, d = c & 63;
#pragma unroll
        for (int i = 0; i < 4; ++i) {
          const int row = m0 + wm + mt * 16 + l4 * 4 + i;
          const int bb = row >> 11, t = row & 2047;
          float v = acc[mt][nt][i] + bv;
          if (which == 0) v *= 0.125f;
          qkv[(size_t)which * 8388608 + ((size_t)((bb * 16 + head) * 2048 + t) << 6) + d] = (bf16_t)v;
        }
      }
    }
  } else {
    float* C = (float*)Cout;
#pragma unroll
    for (int mt = 0; mt < 4; ++mt) {
#pragma unroll
      for (int nt = 0; nt < 4; ++nt) {
        const int col = n0 + wn + nt * 16 + l15;
        const float bv = bias[col];
#pragma unroll
        for (int i = 0; i < 4; ++i) {
          const int row = m0 + wm + mt * 16 + l4 * 4 + i;
          C[(size_t)row * N + col] = acc[mt][nt][i] + bv;
        }
      }
    }
  }
}

// ---------------- one flash tile-step, register state, guaranteed inline ----
static __device__ __forceinline__ void attn_step(
    const bf16_t* Kt, const bf16_t* VT, bf16_t* Ps,
    const int wave, const int l15, const int l4,
    const bf16x8 aq0, const bf16x8 aq1,
    f32x4& m_i, f32x4& l_i,
    f32x4& o0, f32x4& o1, f32x4& o2, f32x4& o3,
    const bool diag)
{
  f32x4 s0 = {}, s1 = {}, s2 = {}, s3 = {};
  {
    bf16x8 b0 = *(const bf16x8*)&Kt[(0 * 16 + l15) * 72 + l4 * 8];
    bf16x8 b1 = *(const bf16x8*)&Kt[(0 * 16 + l15) * 72 + 32 + l4 * 8];
    s0 = __builtin_amdgcn_mfma_f32_16x16x32_bf16(aq0, b0, s0, 0, 0, 0);
    s0 = __builtin_amdgcn_mfma_f32_16x16x32_bf16(aq1, b1, s0, 0, 0, 0);
  }
  {
    bf16x8 b0 = *(const bf16x8*)&Kt[(1 * 16 + l15) * 72 + l4 * 8];
    bf16x8 b1 = *(const bf16x8*)&Kt[(1 * 16 + l15) * 72 + 32 + l4 * 8];
    s1 = __builtin_amdgcn_mfma_f32_16x16x32_bf16(aq0, b0, s1, 0, 0, 0);
    s1 = __builtin_amdgcn_mfma_f32_16x16x32_bf16(aq1, b1, s1, 0, 0, 0);
  }
  {
    bf16x8 b0 = *(const bf16x8*)&Kt[(2 * 16 + l15) * 72 + l4 * 8];
    bf16x8 b1 = *(const bf16x8*)&Kt[(2 * 16 + l15) * 72 + 32 + l4 * 8];
    s2 = __builtin_amdgcn_mfma_f32_16x16x32_bf16(aq0, b0, s2, 0, 0, 0);
    s2 = __builtin_amdgcn_mfma_f32_16x16x32_bf16(aq1, b1, s2, 0, 0, 0);
  }
  {
    bf16x8 b0 = *(const bf16x8*)&Kt[(3 * 16 + l15) * 72 + l4 * 8];
    bf16x8 b1 = *(const bf16x8*)&Kt[(3 * 16 + l15) * 72 + 32 + l4 * 8];
    s3 = __builtin_amdgcn_mfma_f32_16x16x32_bf16(aq0, b0, s3, 0, 0, 0);
    s3 = __builtin_amdgcn_mfma_f32_16x16x32_bf16(aq1, b1, s3, 0, 0, 0);
  }
  if (diag) {
#pragma unroll
    for (int i = 0; i < 4; ++i) {
      const int q = wave * 16 + l4 * 4 + i;
      if (0 * 16 + l15 > q) s0[i] = -1e30f;
      if (1 * 16 + l15 > q) s1[i] = -1e30f;
      if (2 * 16 + l15 > q) s2[i] = -1e30f;
      if (3 * 16 + l15 > q) s3[i] = -1e30f;
    }
  }
  f32x4 pm;
#pragma unroll
  for (int i = 0; i < 4; ++i)
    pm[i] = fmaxf(fmaxf(s0[i], s1[i]), fmaxf(s2[i], s3[i]));
#pragma unroll
  for (int i = 0; i < 4; ++i) {
    pm[i] = fmaxf(pm[i], __shfl_xor(pm[i], 1));
    pm[i] = fmaxf(pm[i], __shfl_xor(pm[i], 2));
    pm[i] = fmaxf(pm[i], __shfl_xor(pm[i], 4));
    pm[i] = fmaxf(pm[i], __shfl_xor(pm[i], 8));
  }
  f32x4 sc;
#pragma unroll
  for (int i = 0; i < 4; ++i) {
    const float mn = fmaxf(m_i[i], pm[i]);
    sc[i] = __expf(m_i[i] - mn);
    m_i[i] = mn;
  }
  f32x4 rsum;
#pragma unroll
  for (int i = 0; i < 4; ++i) {
    s0[i] = __expf(s0[i] - m_i[i]);
    s1[i] = __expf(s1[i] - m_i[i]);
    s2[i] = __expf(s2[i] - m_i[i]);
    s3[i] = __expf(s3[i] - m_i[i]);
    rsum[i] = (s0[i] + s1[i]) + (s2[i] + s3[i]);
  }
#pragma unroll
  for (int i = 0; i < 4; ++i) {
    rsum[i] += __shfl_xor(rsum[i], 1);
    rsum[i] += __shfl_xor(rsum[i], 2);
    rsum[i] += __shfl_xor(rsum[i], 4);
    rsum[i] += __shfl_xor(rsum[i], 8);
    l_i[i] = l_i[i] * sc[i] + rsum[i];
  }
#pragma unroll
  for (int i = 0; i < 4; ++i) {
    o0[i] *= sc[i]; o1[i] *= sc[i]; o2[i] *= sc[i]; o3[i] *= sc[i];
  }
  // P -> LDS, XOR-swizzled so the 4 l4 row-groups hit disjoint banks
#pragma unroll
  for (int i = 0; i < 4; ++i) {
    const int row = wave * 16 + l4 * 4 + i;
    const int swz = l4 << 4;
    Ps[row * 72 + ((0 * 16 + l15) ^ swz)] = (bf16_t)s0[i];
    Ps[row * 72 + ((1 * 16 + l15) ^ swz)] = (bf16_t)s1[i];
    Ps[row * 72 + ((2 * 16 + l15) ^ swz)] = (bf16_t)s2[i];
    Ps[row * 72 + ((3 * 16 + l15) ^ swz)] = (bf16_t)s3[i];
  }
  const int prow = wave * 16 + l15;
  const int psw = ((prow >> 2) & 3) << 4;
  bf16x8 pa0 = *(const bf16x8*)&Ps[prow * 72 + ((l4 * 8) ^ psw)];
  bf16x8 pa1 = *(const bf16x8*)&Ps[prow * 72 + ((32 + l4 * 8) ^ psw)];
  {
    bf16x8 vb0 = *(const bf16x8*)&VT[(0 * 16 + l15) * 72 + l4 * 8];
    bf16x8 vb1 = *(const bf16x8*)&VT[(0 * 16 + l15) * 72 + 32 + l4 * 8];
    o0 = __builtin_amdgcn_mfma_f32_16x16x32_bf16(pa0, vb0, o0, 0, 0, 0);
    o0 = __builtin_amdgcn_mfma_f32_16x16x32_bf16(pa1, vb1, o0, 0, 0, 0);
  }
  {
    bf16x8 vb0 = *(const bf16x8*)&VT[(1 * 16 + l15) * 72 + l4 * 8];
    bf16x8 vb1 = *(const bf16x8*)&VT[(1 * 16 + l15) * 72 + 32 + l4 * 8];
    o1 = __builtin_amdgcn_mfma_f32_16x16x32_bf16(pa0, vb0, o1, 0, 0, 0);
    o1 = __builtin_amdgcn_mfma_f32_16x16x32_bf16(pa1, vb1, o1, 0, 0, 0);
  }
  {
    bf16x8 vb0 = *(const bf16x8*)&VT[(2 * 16 + l15) * 72 + l4 * 8];
    bf16x8 vb1 = *(const bf16x8*)&VT[(2 * 16 + l15) * 72 + 32 + l4 * 8];
    o2 = __builtin_amdgcn_mfma_f32_16x16x32_bf16(pa0, vb0, o2, 0, 0, 0);
    o2 = __builtin_amdgcn_mfma_f32_16x16x32_bf16(pa1, vb1, o2, 0, 0, 0);
  }
  {
    bf16x8 vb0 = *(const bf16x8*)&VT[(3 * 16 + l15) * 72 + l4 * 8];
    bf16x8 vb1 = *(const bf16x8*)&VT[(3 * 16 + l15) * 72 + 32 + l4 * 8];
    o3 = __builtin_amdgcn_mfma_f32_16x16x32_bf16(pa0, vb0, o3, 0, 0, 0);
    o3 = __builtin_amdgcn_mfma_f32_16x16x32_bf16(pa1, vb1, o3, 0, 0, 0);
  }
}

// ---------------- causal flash attention, single q-tile / block ----------
// grid: (32, B*nh). qt = 31 - blockIdx.x (longest blocks dispatch first ->
// short blocks backfill the drain). Next K/V tile prefetched into registers
// during compute (T14 async-stage split) -- no vmcnt drain at barriers.
__global__ __launch_bounds__(256) void flash_attn(
    const bf16_t* __restrict__ Qg, const bf16_t* __restrict__ Kg,
    const bf16_t* __restrict__ Vg, bf16_t* __restrict__ Y)
{
  const int T = 2048, HS = 64;
  const int qt = 31 - blockIdx.x;
  const int bh = blockIdx.y;
  const int q0 = qt * 64;
  const size_t base = (size_t)bh * T * HS;

  __shared__ bf16_t Kt[64 * 72];
  __shared__ bf16_t VT[64 * 72];
  __shared__ bf16_t Ps[64 * 72];

  const int tid = threadIdx.x;
  const int wave = tid >> 6, lane = tid & 63;
  const int l15 = lane & 15, l4 = lane >> 4;

  // Q fragments hoisted to registers
  bf16x8 aq0, aq1;
  {
    const bf16_t* qr = Qg + base + (size_t)(q0 + wave * 16 + l15) * HS;
    aq0 = *(const bf16x8*)(qr + l4 * 8);
    aq1 = *(const bf16x8*)(qr + 32 + l4 * 8);
  }

  f32x4 m_i, l_i;
  f32x4 o0 = {}, o1 = {}, o2 = {}, o3 = {};
#pragma unroll
  for (int i = 0; i < 4; ++i) { m_i[i] = -1e30f; l_i[i] = 0.f; }

  // staging geometry
  const int kr = tid >> 2;            // K row   (4 threads/row)
  const int c16 = (tid & 3) * 16;     // K col chunk
  const int vk = lane;                // V row (per wave: all 64)
  const int d0 = wave * 16;           // V col chunk per wave

  // prefetch tile 0 into registers
  bf16x8 kA, kB, vA, vB;
  {
    const bf16_t* ks = Kg + base + (size_t)kr * HS + c16;
    kA = *(const bf16x8*)ks;
    kB = *(const bf16x8*)(ks + 8);
    const bf16_t* vs = Vg + base + (size_t)vk * HS + d0;
    vA = *(const bf16x8*)vs;
    vB = *(const bf16x8*)(vs + 8);
  }

  for (int kt = 0; kt <= qt; ++kt) {
    __syncthreads();  // prior step's LDS reads complete before overwrite
    // registers -> LDS (waits vmcnt for the prefetch issued last iter)
    *(bf16x8*)&Kt[kr * 72 + c16] = kA;
    *(bf16x8*)&Kt[kr * 72 + c16 + 8] = kB;
#pragma unroll
    for (int j = 0; j < 8; ++j) {
      VT[(d0 + j) * 72 + vk] = vA[j];
      VT[(d0 + 8 + j) * 72 + vk] = vB[j];
    }
    // issue next tile's loads; they fly during compute
    if (kt < qt) {
      const bf16_t* ks = Kg + base + (size_t)((kt + 1) * 64 + kr) * HS + c16;
      kA = *(const bf16x8*)ks;
      kB = *(const bf16x8*)(ks + 8);
      const bf16_t* vs = Vg + base + (size_t)((kt + 1) * 64 + vk) * HS + d0;
      vA = *(const bf16x8*)vs;
      vB = *(const bf16x8*)(vs + 8);
    }
    __syncthreads();
    attn_step(Kt, VT, Ps, wave, l15, l4, aq0, aq1, m_i, l_i, o0, o1, o2, o3, kt == qt);
  }

  // epilogue: O / l, write (B,T,C) bf16
  const int b = bh >> 4, h = bh & 15;
#pragma unroll
  for (int i = 0; i < 4; ++i) {
    const int q = q0 + wave * 16 + l4 * 4 + i;
    bf16_t* y = Y + ((size_t)(b * T + q)) * 1024 + h * 64 + l15;
    const float il = 1.f / l_i[i];
    y[0]  = (bf16_t)(o0[i] * il);
    y[16] = (bf16_t)(o1[i] * il);
    y[32] = (bf16_t)(o2[i] * il);
    y[48] = (bf16_t)(o3[i] * il);
  }
}

// ---------------- launch ----------------
extern "C" void kernel_launch(void* const* d_in, const int* in_sizes, int n_in,
                              void* d_out, int out_size, void* d_ws, size_t ws_size,
                              hipStream_t stream) {
  const float* x      = (const float*)d_in[0];
  const float* w_attn = (const float*)d_in[1];
  const float* b_attn = (const float*)d_in[2];
  const float* w_proj = (const float*)d_in[3];
  const float* b_proj = (const float*)d_in[4];
  float* out = (float*)d_out;

  char* ws = (char*)d_ws;
  bf16_t* xb   = (bf16_t*)(ws);
  bf16_t* wab  = (bf16_t*)(ws + 16777216);
  bf16_t* wpb  = (bf16_t*)(ws + 23068672);
  bf16_t* qkvb = (bf16_t*)(ws + 25165824);
  bf16_t* yb   = (bf16_t*)(ws + 75497472);

  cvt_f32_bf16<<<8192, 256, 0, stream>>>(x, xb, 2097152);
  cvt_f32_bf16<<<3072, 256, 0, stream>>>(w_attn, wab, 786432);
  cvt_f32_bf16<<<1024, 256, 0, stream>>>(w_proj, wpb, 262144);

  dim3 g1(24, 64);
  gemm_bt<0><<<g1, 256, 0, stream>>>(xb, wab, b_attn, (void*)qkvb, 8192, 3072, 1024);

  dim3 g2(32, 64);
  flash_attn<<<g2, 256, 0, stream>>>(qkvb, qkvb + 8388608, qkvb + 16777216, yb);

  dim3 g3(8, 64);
  gemm_bt<1><<<g3, 256, 0, stream>>>(yb, wpb, b_proj, (void*)out, 8192, 1024, 1024);
}

// Round 5
// 336.394 us; speedup vs baseline: 1.2747x; 1.0958x over previous
//
#include <hip/hip_runtime.h>
#include <hip/hip_bf16.h>
#include <stdint.h>

typedef __bf16 bf16_t;
typedef __bf16 bf16x8 __attribute__((ext_vector_type(8)));
typedef __bf16 bf16x4 __attribute__((ext_vector_type(4)));
typedef float f32x4 __attribute__((ext_vector_type(4)));

#define AS1 __attribute__((address_space(1)))
#define AS3 __attribute__((address_space(3)))

static __device__ __forceinline__ void gload_lds16(const void* g, void* l) {
  __builtin_amdgcn_global_load_lds((const AS1 void*)g, (AS3 void*)l, 16, 0, 0);
}

// ---------------- fp32 -> bf16 convert (vectorized x4) ----------------
__global__ void cvt_f32_bf16(const float* __restrict__ in, bf16_t* __restrict__ out, int n4) {
  int i = blockIdx.x * blockDim.x + threadIdx.x;
  if (i >= n4) return;
  float4 v = ((const float4*)in)[i];
  bf16x4 o;
  o[0] = (bf16_t)v.x; o[1] = (bf16_t)v.y; o[2] = (bf16_t)v.z; o[3] = (bf16_t)v.w;
  *(bf16x4*)(out + (size_t)i * 4) = o;
}

// ---------------- GEMM C = A(MxK) * B(NxK)^T, bf16 in, fp32 acc ----------------
template<int MODE>
__global__ __launch_bounds__(256) void gemm_bt(
    const bf16_t* __restrict__ A, const bf16_t* __restrict__ Bw,
    const float* __restrict__ bias, void* __restrict__ Cout,
    int M, int N, int K)
{
  __shared__ bf16_t As[128 * 32];
  __shared__ bf16_t Bs[128 * 32];
  const int tid = threadIdx.x;
  const int wave = tid >> 6, lane = tid & 63;
  const int l15 = lane & 15, l4 = lane >> 4;
  const int m0 = blockIdx.y * 128, n0 = blockIdx.x * 128;
  const int wm = (wave >> 1) * 64, wn = (wave & 1) * 64;
  f32x4 acc[4][4] = {};

  const int r = tid >> 2;
  const int cb = (tid & 3) * 16;
  const char* gA0 = (const char*)(A + (size_t)(m0 + r) * K) + cb;
  const char* gA1 = (const char*)(A + (size_t)(m0 + 64 + r) * K) + cb;
  const char* gB0 = (const char*)(Bw + (size_t)(n0 + r) * K) + cb;
  const char* gB1 = (const char*)(Bw + (size_t)(n0 + 64 + r) * K) + cb;
  char* lA = (char*)As + tid * 16;
  char* lB = (char*)Bs + tid * 16;

  for (int k0 = 0; k0 < K; k0 += 32) {
    const size_t koff = (size_t)k0 * 2;
    gload_lds16(gA0 + koff, lA);
    gload_lds16(gA1 + koff, lA + 4096);
    gload_lds16(gB0 + koff, lB);
    gload_lds16(gB1 + koff, lB + 4096);
    __syncthreads();
    bf16x8 af[4], bfr[4];
#pragma unroll
    for (int mt = 0; mt < 4; ++mt)
      af[mt] = *(const bf16x8*)&As[(wm + mt * 16 + l15) * 32 + l4 * 8];
#pragma unroll
    for (int nt = 0; nt < 4; ++nt)
      bfr[nt] = *(const bf16x8*)&Bs[(wn + nt * 16 + l15) * 32 + l4 * 8];
#pragma unroll
    for (int mt = 0; mt < 4; ++mt)
#pragma unroll
      for (int nt = 0; nt < 4; ++nt)
        acc[mt][nt] = __builtin_amdgcn_mfma_f32_16x16x32_bf16(af[mt], bfr[nt], acc[mt][nt], 0, 0, 0);
    __syncthreads();
  }

  if (MODE == 0) {
    bf16_t* qkv = (bf16_t*)Cout;
#pragma unroll
    for (int mt = 0; mt < 4; ++mt) {
#pragma unroll
      for (int nt = 0; nt < 4; ++nt) {
        const int col = n0 + wn + nt * 16 + l15;
        const float bv = bias[col];
        const int which = col >> 10;
        const int c = col & 1023;
        const int head = c >> 6, d = c & 63;
#pragma unroll
        for (int i = 0; i < 4; ++i) {
          const int row = m0 + wm + mt * 16 + l4 * 4 + i;
          const int bb = row >> 11, t = row & 2047;
          float v = acc[mt][nt][i] + bv;
          if (which == 0) v *= 0.125f;
          qkv[(size_t)which * 8388608 + ((size_t)((bb * 16 + head) * 2048 + t) << 6) + d] = (bf16_t)v;
        }
      }
    }
  } else {
    float* C = (float*)Cout;
#pragma unroll
    for (int mt = 0; mt < 4; ++mt) {
#pragma unroll
      for (int nt = 0; nt < 4; ++nt) {
        const int col = n0 + wn + nt * 16 + l15;
        const float bv = bias[col];
#pragma unroll
        for (int i = 0; i < 4; ++i) {
          const int row = m0 + wm + mt * 16 + l4 * 4 + i;
          C[(size_t)row * N + col] = acc[mt][nt][i] + bv;
        }
      }
    }
  }
}

// ---------------- one 16-row flash half-step, register state, inline ----
// Kt: linear [64][64] with chunk-XOR swizzle (chunk c of row r stored at
// phys chunk c^(r&7)). VT: [d][k] padded 72. Ps: wave-private rows, padded
// 72 + XOR swizzle.
static __device__ __forceinline__ void attn_half(
    const bf16_t* Kt, const bf16_t* VT, bf16_t* Ps,
    const int l15, const int l4, const int prow_base, const int qbase,
    const bf16x8 aq0, const bf16x8 aq1,
    f32x4& m_i, f32x4& l_i,
    f32x4& o0, f32x4& o1, f32x4& o2, f32x4& o3,
    const bool diag)
{
  f32x4 s0 = {}, s1 = {}, s2 = {}, s3 = {};
  {
    const int rr = 0 * 16 + l15;
    bf16x8 b0 = *(const bf16x8*)((const char*)Kt + rr * 128 + ((l4 ^ (rr & 7)) << 4));
    bf16x8 b1 = *(const bf16x8*)((const char*)Kt + rr * 128 + (((l4 + 4) ^ (rr & 7)) << 4));
    s0 = __builtin_amdgcn_mfma_f32_16x16x32_bf16(aq0, b0, s0, 0, 0, 0);
    s0 = __builtin_amdgcn_mfma_f32_16x16x32_bf16(aq1, b1, s0, 0, 0, 0);
  }
  {
    const int rr = 1 * 16 + l15;
    bf16x8 b0 = *(const bf16x8*)((const char*)Kt + rr * 128 + ((l4 ^ (rr & 7)) << 4));
    bf16x8 b1 = *(const bf16x8*)((const char*)Kt + rr * 128 + (((l4 + 4) ^ (rr & 7)) << 4));
    s1 = __builtin_amdgcn_mfma_f32_16x16x32_bf16(aq0, b0, s1, 0, 0, 0);
    s1 = __builtin_amdgcn_mfma_f32_16x16x32_bf16(aq1, b1, s1, 0, 0, 0);
  }
  {
    const int rr = 2 * 16 + l15;
    bf16x8 b0 = *(const bf16x8*)((const char*)Kt + rr * 128 + ((l4 ^ (rr & 7)) << 4));
    bf16x8 b1 = *(const bf16x8*)((const char*)Kt + rr * 128 + (((l4 + 4) ^ (rr & 7)) << 4));
    s2 = __builtin_amdgcn_mfma_f32_16x16x32_bf16(aq0, b0, s2, 0, 0, 0);
    s2 = __builtin_amdgcn_mfma_f32_16x16x32_bf16(aq1, b1, s2, 0, 0, 0);
  }
  {
    const int rr = 3 * 16 + l15;
    bf16x8 b0 = *(const bf16x8*)((const char*)Kt + rr * 128 + ((l4 ^ (rr & 7)) << 4));
    bf16x8 b1 = *(const bf16x8*)((const char*)Kt + rr * 128 + (((l4 + 4) ^ (rr & 7)) << 4));
    s3 = __builtin_amdgcn_mfma_f32_16x16x32_bf16(aq0, b0, s3, 0, 0, 0);
    s3 = __builtin_amdgcn_mfma_f32_16x16x32_bf16(aq1, b1, s3, 0, 0, 0);
  }
  if (diag) {
#pragma unroll
    for (int i = 0; i < 4; ++i) {
      const int q = qbase + l4 * 4 + i;
      if (0 * 16 + l15 > q) s0[i] = -1e30f;
      if (1 * 16 + l15 > q) s1[i] = -1e30f;
      if (2 * 16 + l15 > q) s2[i] = -1e30f;
      if (3 * 16 + l15 > q) s3[i] = -1e30f;
    }
  }
  f32x4 pm;
#pragma unroll
  for (int i = 0; i < 4; ++i)
    pm[i] = fmaxf(fmaxf(s0[i], s1[i]), fmaxf(s2[i], s3[i]));
#pragma unroll
  for (int i = 0; i < 4; ++i) {
    pm[i] = fmaxf(pm[i], __shfl_xor(pm[i], 1));
    pm[i] = fmaxf(pm[i], __shfl_xor(pm[i], 2));
    pm[i] = fmaxf(pm[i], __shfl_xor(pm[i], 4));
    pm[i] = fmaxf(pm[i], __shfl_xor(pm[i], 8));
  }
  f32x4 sc;
#pragma unroll
  for (int i = 0; i < 4; ++i) {
    const float mn = fmaxf(m_i[i], pm[i]);
    sc[i] = __expf(m_i[i] - mn);
    m_i[i] = mn;
  }
  f32x4 rsum;
#pragma unroll
  for (int i = 0; i < 4; ++i) {
    s0[i] = __expf(s0[i] - m_i[i]);
    s1[i] = __expf(s1[i] - m_i[i]);
    s2[i] = __expf(s2[i] - m_i[i]);
    s3[i] = __expf(s3[i] - m_i[i]);
    rsum[i] = (s0[i] + s1[i]) + (s2[i] + s3[i]);
  }
#pragma unroll
  for (int i = 0; i < 4; ++i) {
    rsum[i] += __shfl_xor(rsum[i], 1);
    rsum[i] += __shfl_xor(rsum[i], 2);
    rsum[i] += __shfl_xor(rsum[i], 4);
    rsum[i] += __shfl_xor(rsum[i], 8);
    l_i[i] = l_i[i] * sc[i] + rsum[i];
  }
#pragma unroll
  for (int i = 0; i < 4; ++i) {
    o0[i] *= sc[i]; o1[i] *= sc[i]; o2[i] *= sc[i]; o3[i] *= sc[i];
  }
  // P -> LDS (wave-private rows), XOR-swizzled cols
#pragma unroll
  for (int i = 0; i < 4; ++i) {
    const int row = prow_base + l4 * 4 + i;
    const int swz = l4 << 4;
    Ps[row * 72 + ((0 * 16 + l15) ^ swz)] = (bf16_t)s0[i];
    Ps[row * 72 + ((1 * 16 + l15) ^ swz)] = (bf16_t)s1[i];
    Ps[row * 72 + ((2 * 16 + l15) ^ swz)] = (bf16_t)s2[i];
    Ps[row * 72 + ((3 * 16 + l15) ^ swz)] = (bf16_t)s3[i];
  }
  const int prow = prow_base + l15;
  const int psw = ((prow >> 2) & 3) << 4;
  bf16x8 pa0 = *(const bf16x8*)&Ps[prow * 72 + ((l4 * 8) ^ psw)];
  bf16x8 pa1 = *(const bf16x8*)&Ps[prow * 72 + ((32 + l4 * 8) ^ psw)];
  {
    bf16x8 vb0 = *(const bf16x8*)&VT[(0 * 16 + l15) * 72 + l4 * 8];
    bf16x8 vb1 = *(const bf16x8*)&VT[(0 * 16 + l15) * 72 + 32 + l4 * 8];
    o0 = __builtin_amdgcn_mfma_f32_16x16x32_bf16(pa0, vb0, o0, 0, 0, 0);
    o0 = __builtin_amdgcn_mfma_f32_16x16x32_bf16(pa1, vb1, o0, 0, 0, 0);
  }
  {
    bf16x8 vb0 = *(const bf16x8*)&VT[(1 * 16 + l15) * 72 + l4 * 8];
    bf16x8 vb1 = *(const bf16x8*)&VT[(1 * 16 + l15) * 72 + 32 + l4 * 8];
    o1 = __builtin_amdgcn_mfma_f32_16x16x32_bf16(pa0, vb0, o1, 0, 0, 0);
    o1 = __builtin_amdgcn_mfma_f32_16x16x32_bf16(pa1, vb1, o1, 0, 0, 0);
  }
  {
    bf16x8 vb0 = *(const bf16x8*)&VT[(2 * 16 + l15) * 72 + l4 * 8];
    bf16x8 vb1 = *(const bf16x8*)&VT[(2 * 16 + l15) * 72 + 32 + l4 * 8];
    o2 = __builtin_amdgcn_mfma_f32_16x16x32_bf16(pa0, vb0, o2, 0, 0, 0);
    o2 = __builtin_amdgcn_mfma_f32_16x16x32_bf16(pa1, vb1, o2, 0, 0, 0);
  }
  {
    bf16x8 vb0 = *(const bf16x8*)&VT[(3 * 16 + l15) * 72 + l4 * 8];
    bf16x8 vb1 = *(const bf16x8*)&VT[(3 * 16 + l15) * 72 + 32 + l4 * 8];
    o3 = __builtin_amdgcn_mfma_f32_16x16x32_bf16(pa0, vb0, o3, 0, 0, 0);
    o3 = __builtin_amdgcn_mfma_f32_16x16x32_bf16(pa1, vb1, o3, 0, 0, 0);
  }
}

// ---------------- causal flash attention, 128-row q-tile / block --------
// grid: (16, B*nh), block 256. Wave w owns q-rows [q0+32w, q0+32w+32) as
// two 16-row halves (independent m/l/o state -> 2x ILP, 32 MFMA/step/wave).
// K staged async via global_load_lds (chunk-XOR swizzle both sides).
// Fully-masked kv-tiles skipped per-wave; all threads still hit barriers.
__global__ __launch_bounds__(256) void flash_attn(
    const bf16_t* __restrict__ Qg, const bf16_t* __restrict__ Kg,
    const bf16_t* __restrict__ Vg, bf16_t* __restrict__ Y)
{
  const int T = 2048, HS = 64;
  const int qt = blockIdx.x;           // 0..15
  const int bh = blockIdx.y;
  const int q0 = qt * 128;
  const size_t base = (size_t)bh * T * HS;

  __shared__ bf16_t Kt[64 * 64];   // linear for global_load_lds, chunk-swizzled
  __shared__ bf16_t VT[64 * 72];   // V transposed [d][k]
  __shared__ bf16_t Ps[64 * 72];   // wave-private P staging

  const int tid = threadIdx.x;
  const int wave = tid >> 6, lane = tid & 63;
  const int l15 = lane & 15, l4 = lane >> 4;

  // Q fragments: half 0 rows q0+32w+l15, half 1 rows q0+32w+16+l15
  bf16x8 aq00, aq01, aq10, aq11;
  {
    const bf16_t* qr = Qg + base + (size_t)(q0 + wave * 32 + l15) * HS;
    aq00 = *(const bf16x8*)(qr + l4 * 8);
    aq01 = *(const bf16x8*)(qr + 32 + l4 * 8);
    qr += 16 * HS;
    aq10 = *(const bf16x8*)(qr + l4 * 8);
    aq11 = *(const bf16x8*)(qr + 32 + l4 * 8);
  }

  f32x4 m0v, l0v, m1v, l1v;
  f32x4 o00 = {}, o01 = {}, o02 = {}, o03 = {};
  f32x4 o10 = {}, o11 = {}, o12 = {}, o13 = {};
#pragma unroll
  for (int i = 0; i < 4; ++i) { m0v[i] = m1v[i] = -1e30f; l0v[i] = l1v[i] = 0.f; }

  // K staging geometry (global_load_lds, source pre-swizzled):
  // dest byte = rd*4096 + tid*16 -> row r = rd*32 + (tid>>3), phys chunk tid&7;
  // logical chunk = (tid&7) ^ (r&7) = (tid&7) ^ ((tid>>3)&7)
  const int krow = tid >> 3;                               // 0..31 (+32 rd=1)
  const int kchunk = ((tid & 7) ^ ((tid >> 3) & 7)) * 8;   // element offset
  // V staging: wave w transposes cols [16w,16w+16) of all 64 rows
  const int vk = lane;
  const int d0 = wave * 16;

  // prefetch V tile 0 into registers
  bf16x8 vA, vB;
  {
    const bf16_t* vs = Vg + base + (size_t)vk * HS + d0;
    vA = *(const bf16x8*)vs;
    vB = *(const bf16x8*)(vs + 8);
  }

  const int ktmax = 2 * qt + 1;
  const int bound = 2 * qt + (wave >> 1);  // last active kv-tile for this wave

  for (int kt = 0; kt <= ktmax; ++kt) {
    __syncthreads();  // prior step's LDS reads done; Kt/VT free
    // K stage: async global->LDS (2 x 16B per thread)
    {
      const bf16_t* ks = Kg + base + (size_t)(kt * 64 + krow) * HS + kchunk;
      gload_lds16(ks, (char*)Kt + tid * 16);
      gload_lds16(ks + 32 * HS, (char*)Kt + 4096 + tid * 16);
    }
    // V stage: registers (prefetched last iter) -> transposed LDS
#pragma unroll
    for (int j = 0; j < 8; ++j) {
      VT[(d0 + j) * 72 + vk] = vA[j];
      VT[(d0 + 8 + j) * 72 + vk] = vB[j];
    }
    __syncthreads();  // drains gload_lds; Kt+VT visible
    // prefetch next V tile; vmcnt drain only at NEXT top barrier (hidden)
    {
      const int nk = (kt < ktmax) ? kt + 1 : kt;
      const bf16_t* vs = Vg + base + (size_t)(nk * 64 + vk) * HS + d0;
      vA = *(const bf16x8*)vs;
      vB = *(const bf16x8*)(vs + 8);
    }
    if (kt <= bound) {
      const bool dg = (kt == bound);
      attn_half(Kt, VT, Ps, l15, l4, wave * 16, (wave * 32) & 63,
                aq00, aq01, m0v, l0v, o00, o01, o02, o03, dg);
      attn_half(Kt, VT, Ps, l15, l4, wave * 16, (wave * 32 + 16) & 63,
                aq10, aq11, m1v, l1v, o10, o11, o12, o13, dg);
    }
  }

  // epilogue: O / l, write (B,T,C) bf16 for both halves
  const int b = bh >> 4, h = bh & 15;
#pragma unroll
  for (int i = 0; i < 4; ++i) {
    const int qa = q0 + wave * 32 + l4 * 4 + i;
    bf16_t* y0 = Y + ((size_t)(b * T + qa)) * 1024 + h * 64 + l15;
    const float il0 = 1.f / l0v[i];
    y0[0]  = (bf16_t)(o00[i] * il0);
    y0[16] = (bf16_t)(o01[i] * il0);
    y0[32] = (bf16_t)(o02[i] * il0);
    y0[48] = (bf16_t)(o03[i] * il0);
    bf16_t* y1 = y0 + 16 * 1024;
    const float il1 = 1.f / l1v[i];
    y1[0]  = (bf16_t)(o10[i] * il1);
    y1[16] = (bf16_t)(o11[i] * il1);
    y1[32] = (bf16_t)(o12[i] * il1);
    y1[48] = (bf16_t)(o13[i] * il1);
  }
}

// ---------------- launch ----------------
extern "C" void kernel_launch(void* const* d_in, const int* in_sizes, int n_in,
                              void* d_out, int out_size, void* d_ws, size_t ws_size,
                              hipStream_t stream) {
  const float* x      = (const float*)d_in[0];
  const float* w_attn = (const float*)d_in[1];
  const float* b_attn = (const float*)d_in[2];
  const float* w_proj = (const float*)d_in[3];
  const float* b_proj = (const float*)d_in[4];
  float* out = (float*)d_out;

  char* ws = (char*)d_ws;
  bf16_t* xb   = (bf16_t*)(ws);
  bf16_t* wab  = (bf16_t*)(ws + 16777216);
  bf16_t* wpb  = (bf16_t*)(ws + 23068672);
  bf16_t* qkvb = (bf16_t*)(ws + 25165824);
  bf16_t* yb   = (bf16_t*)(ws + 75497472);

  cvt_f32_bf16<<<8192, 256, 0, stream>>>(x, xb, 2097152);
  cvt_f32_bf16<<<3072, 256, 0, stream>>>(w_attn, wab, 786432);
  cvt_f32_bf16<<<1024, 256, 0, stream>>>(w_proj, wpb, 262144);

  dim3 g1(24, 64);
  gemm_bt<0><<<g1, 256, 0, stream>>>(xb, wab, b_attn, (void*)qkvb, 8192, 3072, 1024);

  dim3 g2(16, 64);
  flash_attn<<<g2, 256, 0, stream>>>(qkvb, qkvb + 8388608, qkvb + 16777216, yb);

  dim3 g3(8, 64);
  gemm_bt<1><<<g3, 256, 0, stream>>>(yb, wpb, b_proj, (void*)out, 8192, 1024, 1024);
}

// Round 6
// 265.123 us; speedup vs baseline: 1.6173x; 1.2688x over previous
//
#include <hip/hip_runtime.h>
#include <hip/hip_bf16.h>
#include <stdint.h>

typedef __bf16 bf16_t;
typedef __bf16 bf16x8 __attribute__((ext_vector_type(8)));
typedef __bf16 bf16x4 __attribute__((ext_vector_type(4)));
typedef float f32x4 __attribute__((ext_vector_type(4)));

#define AS1 __attribute__((address_space(1)))
#define AS3 __attribute__((address_space(3)))

static __device__ __forceinline__ void gload_lds16(const void* g, void* l) {
  __builtin_amdgcn_global_load_lds((const AS1 void*)g, (AS3 void*)l, 16, 0, 0);
}

// v_cvt_pk_bf16_f32: dst.lo = bf16(lo), dst.hi = bf16(hi)
static __device__ __forceinline__ uint32_t cvt_pk(float lo, float hi) {
  uint32_t r;
  asm("v_cvt_pk_bf16_f32 %0, %1, %2" : "=v"(r) : "v"(lo), "v"(hi));
  return r;
}

// ---------------- fp32 -> bf16 convert (vectorized x4) ----------------
__global__ void cvt_f32_bf16(const float* __restrict__ in, bf16_t* __restrict__ out, int n4) {
  int i = blockIdx.x * blockDim.x + threadIdx.x;
  if (i >= n4) return;
  float4 v = ((const float4*)in)[i];
  bf16x4 o;
  o[0] = (bf16_t)v.x; o[1] = (bf16_t)v.y; o[2] = (bf16_t)v.z; o[3] = (bf16_t)v.w;
  *(bf16x4*)(out + (size_t)i * 4) = o;
}

// ---------------- GEMM C = A(MxK) * B(NxK)^T, bf16 in, fp32 acc ----------------
// MODE 0: qkv epilogue. q: scaled 0.125, (bh,t,d). k: (bh,t,d).
//         v: TRANSPOSED (bh,d,t) with per-64-tile k-permutation sigma
//         (k bits [f|u|l4|c] -> pos bits [f|l4|u|c]) so flash PV fragments
//         are lane-local packs.
// MODE 1: proj epilogue (+bias, fp32 row-major out)
template<int MODE>
__global__ __launch_bounds__(256) void gemm_bt(
    const bf16_t* __restrict__ A, const bf16_t* __restrict__ Bw,
    const float* __restrict__ bias, void* __restrict__ Cout,
    int M, int N, int K)
{
  __shared__ bf16_t As[128 * 32];
  __shared__ bf16_t Bs[128 * 32];
  const int tid = threadIdx.x;
  const int wave = tid >> 6, lane = tid & 63;
  const int l15 = lane & 15, l4 = lane >> 4;
  const int m0 = blockIdx.y * 128, n0 = blockIdx.x * 128;
  const int wm = (wave >> 1) * 64, wn = (wave & 1) * 64;
  f32x4 acc[4][4] = {};

  const int r = tid >> 2;
  const int cb = (tid & 3) * 16;
  const char* gA0 = (const char*)(A + (size_t)(m0 + r) * K) + cb;
  const char* gA1 = (const char*)(A + (size_t)(m0 + 64 + r) * K) + cb;
  const char* gB0 = (const char*)(Bw + (size_t)(n0 + r) * K) + cb;
  const char* gB1 = (const char*)(Bw + (size_t)(n0 + 64 + r) * K) + cb;
  char* lA = (char*)As + tid * 16;
  char* lB = (char*)Bs + tid * 16;

  for (int k0 = 0; k0 < K; k0 += 32) {
    const size_t koff = (size_t)k0 * 2;
    gload_lds16(gA0 + koff, lA);
    gload_lds16(gA1 + koff, lA + 4096);
    gload_lds16(gB0 + koff, lB);
    gload_lds16(gB1 + koff, lB + 4096);
    __syncthreads();
    bf16x8 af[4], bfr[4];
#pragma unroll
    for (int mt = 0; mt < 4; ++mt)
      af[mt] = *(const bf16x8*)&As[(wm + mt * 16 + l15) * 32 + l4 * 8];
#pragma unroll
    for (int nt = 0; nt < 4; ++nt)
      bfr[nt] = *(const bf16x8*)&Bs[(wn + nt * 16 + l15) * 32 + l4 * 8];
#pragma unroll
    for (int mt = 0; mt < 4; ++mt)
#pragma unroll
      for (int nt = 0; nt < 4; ++nt)
        acc[mt][nt] = __builtin_amdgcn_mfma_f32_16x16x32_bf16(af[mt], bfr[nt], acc[mt][nt], 0, 0, 0);
    __syncthreads();
  }

  if (MODE == 0) {
    bf16_t* qkv = (bf16_t*)Cout;
#pragma unroll
    for (int mt = 0; mt < 4; ++mt) {
#pragma unroll
      for (int nt = 0; nt < 4; ++nt) {
        const int col = n0 + wn + nt * 16 + l15;
        const float bv = bias[col];
        const int which = col >> 10;
        const int c = col & 1023;
        const int head = c >> 6, d = c & 63;
#pragma unroll
        for (int i = 0; i < 4; ++i) {
          const int row = m0 + wm + mt * 16 + l4 * 4 + i;
          const int bb = row >> 11, t = row & 2047;
          const int bh2 = bb * 16 + head;
          float v = acc[mt][nt][i] + bv;
          size_t idx;
          if (which == 0) {
            v *= 0.125f;
            idx = ((size_t)(bh2 * 2048 + t) << 6) + d;
          } else if (which == 1) {
            idx = 8388608 + ((size_t)(bh2 * 2048 + t) << 6) + d;
          } else {
            const int ko = t & 63;
            const int pos = (ko & 0x20) | ((ko & 0x0C) << 1) | ((ko & 0x10) >> 2) | (ko & 3);
            idx = 16777216 + (size_t)(bh2 * 64 + d) * 2048 + (t & ~63) + pos;
          }
          qkv[idx] = (bf16_t)v;
        }
      }
    }
  } else {
    float* C = (float*)Cout;
#pragma unroll
    for (int mt = 0; mt < 4; ++mt) {
#pragma unroll
      for (int nt = 0; nt < 4; ++nt) {
        const int col = n0 + wn + nt * 16 + l15;
        const float bv = bias[col];
#pragma unroll
        for (int i = 0; i < 4; ++i) {
          const int row = m0 + wm + mt * 16 + l4 * 4 + i;
          C[(size_t)row * N + col] = acc[mt][nt][i] + bv;
        }
      }
    }
  }
}

// ---------------- one 16-q flash half-step, swapped-operand, in-lane SM ----
// S^T = mfma(Kfrag, Qfrag): lane (l4,l15) holds S[q=l15][k=t*16+l4*4+i].
// Softmax fully in-lane (2 shuffles). PV: O^T += mfma(Vfrag, pack(P));
// V stored k-permuted so pack is lane-local. pA/pB: LDS read bases
// (chunk-XOR swizzled); K tiles at +t*2048, V tiles at +16384+t*2048.
static __device__ __forceinline__ void attn_half(
    const char* pA, const char* pB, const int kb,
    const bf16x8 aq0, const bf16x8 aq1,
    float& m_i, float& l_i,
    f32x4& o0, f32x4& o1, f32x4& o2, f32x4& o3,
    const bool diag, const int qb)
{
  f32x4 s0 = {}, s1 = {}, s2 = {}, s3 = {};
  s0 = __builtin_amdgcn_mfma_f32_16x16x32_bf16(*(const bf16x8*)(pA + 0), aq0, s0, 0, 0, 0);
  s0 = __builtin_amdgcn_mfma_f32_16x16x32_bf16(*(const bf16x8*)(pB + 0), aq1, s0, 0, 0, 0);
  s1 = __builtin_amdgcn_mfma_f32_16x16x32_bf16(*(const bf16x8*)(pA + 2048), aq0, s1, 0, 0, 0);
  s1 = __builtin_amdgcn_mfma_f32_16x16x32_bf16(*(const bf16x8*)(pB + 2048), aq1, s1, 0, 0, 0);
  s2 = __builtin_amdgcn_mfma_f32_16x16x32_bf16(*(const bf16x8*)(pA + 4096), aq0, s2, 0, 0, 0);
  s2 = __builtin_amdgcn_mfma_f32_16x16x32_bf16(*(const bf16x8*)(pB + 4096), aq1, s2, 0, 0, 0);
  s3 = __builtin_amdgcn_mfma_f32_16x16x32_bf16(*(const bf16x8*)(pA + 6144), aq0, s3, 0, 0, 0);
  s3 = __builtin_amdgcn_mfma_f32_16x16x32_bf16(*(const bf16x8*)(pB + 6144), aq1, s3, 0, 0, 0);

  if (diag) {
#pragma unroll
    for (int i = 0; i < 4; ++i) {
      if (kb + i > qb)      s0[i] = -1e30f;
      if (16 + kb + i > qb) s1[i] = -1e30f;
      if (32 + kb + i > qb) s2[i] = -1e30f;
      if (48 + kb + i > qb) s3[i] = -1e30f;
    }
  }

  float pm = fmaxf(fmaxf(fmaxf(s0[0], s0[1]), fmaxf(s0[2], s0[3])),
                   fmaxf(fmaxf(s1[0], s1[1]), fmaxf(s1[2], s1[3])));
  pm = fmaxf(pm, fmaxf(fmaxf(fmaxf(s2[0], s2[1]), fmaxf(s2[2], s2[3])),
                       fmaxf(fmaxf(s3[0], s3[1]), fmaxf(s3[2], s3[3]))));
  pm = fmaxf(pm, __shfl_xor(pm, 16));
  pm = fmaxf(pm, __shfl_xor(pm, 32));

  const float mn = fmaxf(m_i, pm);
  const float sc = __expf(m_i - mn);
  m_i = mn;
#pragma unroll
  for (int i = 0; i < 4; ++i) {
    s0[i] = __expf(s0[i] - mn);
    s1[i] = __expf(s1[i] - mn);
    s2[i] = __expf(s2[i] - mn);
    s3[i] = __expf(s3[i] - mn);
  }
  float rs = ((s0[0] + s0[1]) + (s0[2] + s0[3])) + ((s1[0] + s1[1]) + (s1[2] + s1[3]))
           + ((s2[0] + s2[1]) + (s2[2] + s2[3])) + ((s3[0] + s3[1]) + (s3[2] + s3[3]));
  rs += __shfl_xor(rs, 16);
  rs += __shfl_xor(rs, 32);
  l_i = l_i * sc + rs;

  o0 *= sc; o1 *= sc; o2 *= sc; o3 *= sc;

  union { uint32_t u[4]; bf16x8 v; } B0, B1;
  B0.u[0] = cvt_pk(s0[0], s0[1]); B0.u[1] = cvt_pk(s0[2], s0[3]);
  B0.u[2] = cvt_pk(s1[0], s1[1]); B0.u[3] = cvt_pk(s1[2], s1[3]);
  B1.u[0] = cvt_pk(s2[0], s2[1]); B1.u[1] = cvt_pk(s2[2], s2[3]);
  B1.u[2] = cvt_pk(s3[0], s3[1]); B1.u[3] = cvt_pk(s3[2], s3[3]);

  o0 = __builtin_amdgcn_mfma_f32_16x16x32_bf16(*(const bf16x8*)(pA + 16384 + 0), B0.v, o0, 0, 0, 0);
  o0 = __builtin_amdgcn_mfma_f32_16x16x32_bf16(*(const bf16x8*)(pB + 16384 + 0), B1.v, o0, 0, 0, 0);
  o1 = __builtin_amdgcn_mfma_f32_16x16x32_bf16(*(const bf16x8*)(pA + 16384 + 2048), B0.v, o1, 0, 0, 0);
  o1 = __builtin_amdgcn_mfma_f32_16x16x32_bf16(*(const bf16x8*)(pB + 16384 + 2048), B1.v, o1, 0, 0, 0);
  o2 = __builtin_amdgcn_mfma_f32_16x16x32_bf16(*(const bf16x8*)(pA + 16384 + 4096), B0.v, o2, 0, 0, 0);
  o2 = __builtin_amdgcn_mfma_f32_16x16x32_bf16(*(const bf16x8*)(pB + 16384 + 4096), B1.v, o2, 0, 0, 0);
  o3 = __builtin_amdgcn_mfma_f32_16x16x32_bf16(*(const bf16x8*)(pA + 16384 + 6144), B0.v, o3, 0, 0, 0);
  o3 = __builtin_amdgcn_mfma_f32_16x16x32_bf16(*(const bf16x8*)(pB + 16384 + 6144), B1.v, o3, 0, 0, 0);
}

// ---------------- causal flash attention, 128-row q-tile / block --------
// grid (16, B*nh), block 256, 4 waves x 32 q-rows (2 halves). K and VT both
// staged async via global_load_lds (chunk-XOR swizzle, pre-swizzled source),
// double-buffered, ONE barrier per step (loads fly across it).
__global__ __launch_bounds__(256) void flash_attn(
    const bf16_t* __restrict__ Qg, const bf16_t* __restrict__ Kg,
    const bf16_t* __restrict__ VTg, bf16_t* __restrict__ Y)
{
  const int T = 2048, HS = 64;
  const int qt = blockIdx.x;           // 0..15
  const int bh = blockIdx.y;
  const int q0 = qt * 128;
  const size_t baseQ = (size_t)bh * T * HS;   // Q,K: (bh, t, d)
  const size_t baseV = (size_t)bh * HS * T;   // VT:  (bh, d, t) k-permuted

  __shared__ char lds[32768];  // [Kt0 8K][Kt1 8K][Vt0 8K][Vt1 8K]

  const int tid = threadIdx.x;
  const int wave = tid >> 6, lane = tid & 63;
  const int l15 = lane & 15, l4 = lane >> 4;

  // Q fragments for 2 halves (rows q0+wave*32+l15 and +16)
  const bf16_t* qr = Qg + baseQ + (size_t)(q0 + wave * 32 + l15) * HS;
  const bf16x8 aq00 = *(const bf16x8*)(qr + l4 * 8);
  const bf16x8 aq01 = *(const bf16x8*)(qr + 32 + l4 * 8);
  const bf16x8 aq10 = *(const bf16x8*)(qr + 16 * HS + l4 * 8);
  const bf16x8 aq11 = *(const bf16x8*)(qr + 16 * HS + 32 + l4 * 8);

  float m0 = -1e30f, l0 = 0.f, m1 = -1e30f, l1 = 0.f;
  f32x4 o00 = {}, o01 = {}, o02 = {}, o03 = {};
  f32x4 o10 = {}, o11 = {}, o12 = {}, o13 = {};

  // staging geometry: dest row = tid>>3 (+32), phys chunk = tid&7,
  // source logical chunk = (tid&7) ^ ((tid>>3)&7)
  const int srow = tid >> 3;
  const int schunk = ((tid & 7) ^ ((tid >> 3) & 7)) * 8;
  char* kdst = lds + tid * 16;
  char* vdst = lds + 16384 + tid * 16;

  // read bases: row=l15(+t*16), phys chunk = l4^(l15&7) (and |4 for hs/k high)
  const int s3b = l15 & 7;
  const int a0 = l15 * 128 + ((l4 ^ s3b) << 4);
  const int a1 = l15 * 128 + (((l4 | 4) ^ s3b) << 4);

  const int ktmax = 2 * qt + 1;
  const int bound = 2 * qt + (wave >> 1);
  const int qb0 = (wave & 1) * 32 + l15;
  const int qb1 = qb0 + 16;
  const int kb = l4 * 4;

  // prologue: stage tile 0 -> buf0
  {
    const bf16_t* ks = Kg + baseQ + (size_t)srow * HS + schunk;
    gload_lds16(ks, kdst);
    gload_lds16(ks + 32 * HS, kdst + 4096);
    const bf16_t* vs = VTg + baseV + (size_t)srow * T + schunk;
    gload_lds16(vs, vdst);
    gload_lds16(vs + 32 * T, vdst + 4096);
  }
  __syncthreads();

  for (int kt = 0; kt <= ktmax; ++kt) {
    // stage next tile into the other buffer; loads fly during compute
    if (kt < ktmax) {
      const int nb = ((kt + 1) & 1) * 8192;
      const bf16_t* ks = Kg + baseQ + (size_t)((kt + 1) * 64 + srow) * HS + schunk;
      gload_lds16(ks, kdst + nb);
      gload_lds16(ks + 32 * HS, kdst + nb + 4096);
      const bf16_t* vs = VTg + baseV + (size_t)srow * T + (kt + 1) * 64 + schunk;
      gload_lds16(vs, vdst + nb);
      gload_lds16(vs + 32 * T, vdst + nb + 4096);
    }
    if (kt <= bound) {
      const char* pA = lds + (kt & 1) * 8192 + a0;
      const char* pB = lds + (kt & 1) * 8192 + a1;
      const bool dg = (kt == bound);
      attn_half(pA, pB, kb, aq00, aq01, m0, l0, o00, o01, o02, o03, dg, qb0);
      attn_half(pA, pB, kb, aq10, aq11, m1, l1, o10, o11, o12, o13, dg, qb1);
    }
    __syncthreads();  // staged tile visible; prior-buffer reads done
  }

  // epilogue: O^T (d = t*16+l4*4+i, q = l15) -> Y (B,T,C) bf16, packed 8B
  const int b = bh >> 4, h = bh & 15;
  {
    const float il = 1.f / l0;
    const int q = q0 + wave * 32 + l15;
    bf16_t* yr = Y + ((size_t)(b * T + q)) * 1024 + h * 64 + l4 * 4;
    uint2 w;
    w.x = cvt_pk(o00[0] * il, o00[1] * il); w.y = cvt_pk(o00[2] * il, o00[3] * il);
    *(uint2*)(yr + 0) = w;
    w.x = cvt_pk(o01[0] * il, o01[1] * il); w.y = cvt_pk(o01[2] * il, o01[3] * il);
    *(uint2*)(yr + 16) = w;
    w.x = cvt_pk(o02[0] * il, o02[1] * il); w.y = cvt_pk(o02[2] * il, o02[3] * il);
    *(uint2*)(yr + 32) = w;
    w.x = cvt_pk(o03[0] * il, o03[1] * il); w.y = cvt_pk(o03[2] * il, o03[3] * il);
    *(uint2*)(yr + 48) = w;
  }
  {
    const float il = 1.f / l1;
    const int q = q0 + wave * 32 + 16 + l15;
    bf16_t* yr = Y + ((size_t)(b * T + q)) * 1024 + h * 64 + l4 * 4;
    uint2 w;
    w.x = cvt_pk(o10[0] * il, o10[1] * il); w.y = cvt_pk(o10[2] * il, o10[3] * il);
    *(uint2*)(yr + 0) = w;
    w.x = cvt_pk(o11[0] * il, o11[1] * il); w.y = cvt_pk(o11[2] * il, o11[3] * il);
    *(uint2*)(yr + 16) = w;
    w.x = cvt_pk(o12[0] * il, o12[1] * il); w.y = cvt_pk(o12[2] * il, o12[3] * il);
    *(uint2*)(yr + 32) = w;
    w.x = cvt_pk(o13[0] * il, o13[1] * il); w.y = cvt_pk(o13[2] * il, o13[3] * il);
    *(uint2*)(yr + 48) = w;
  }
}

// ---------------- launch ----------------
extern "C" void kernel_launch(void* const* d_in, const int* in_sizes, int n_in,
                              void* d_out, int out_size, void* d_ws, size_t ws_size,
                              hipStream_t stream) {
  const float* x      = (const float*)d_in[0];
  const float* w_attn = (const float*)d_in[1];
  const float* b_attn = (const float*)d_in[2];
  const float* w_proj = (const float*)d_in[3];
  const float* b_proj = (const float*)d_in[4];
  float* out = (float*)d_out;

  char* ws = (char*)d_ws;
  bf16_t* xb   = (bf16_t*)(ws);
  bf16_t* wab  = (bf16_t*)(ws + 16777216);
  bf16_t* wpb  = (bf16_t*)(ws + 23068672);
  bf16_t* qkvb = (bf16_t*)(ws + 25165824);   // q | k | vT (8M elems each)
  bf16_t* yb   = (bf16_t*)(ws + 75497472);

  cvt_f32_bf16<<<8192, 256, 0, stream>>>(x, xb, 2097152);
  cvt_f32_bf16<<<3072, 256, 0, stream>>>(w_attn, wab, 786432);
  cvt_f32_bf16<<<1024, 256, 0, stream>>>(w_proj, wpb, 262144);

  dim3 g1(24, 64);
  gemm_bt<0><<<g1, 256, 0, stream>>>(xb, wab, b_attn, (void*)qkvb, 8192, 3072, 1024);

  dim3 g2(16, 64);
  flash_attn<<<g2, 256, 0, stream>>>(qkvb, qkvb + 8388608, qkvb + 16777216, yb);

  dim3 g3(8, 64);
  gemm_bt<1><<<g3, 256, 0, stream>>>(yb, wpb, b_proj, (void*)out, 8192, 1024, 1024);
}